// Round 2
// baseline (7081.149 us; speedup 1.0000x reference)
//
#include <hip/hip_runtime.h>
#include <hip/hip_bf16.h>
#include <math.h>

#define BB 2
#define TT 1024
#define VV 32000
#define HH 2048
#define HK 16
#define HV 32
#define DK 128
#define DV 128
#define QKD 2048
#define VD 4096
#define CONVD 8192
#define QKVZ 12288
#define MM (BB*TT)          // 2048
#define FEPS 1e-6f
#define CH 16

__device__ __forceinline__ float wave64_sum(float x) {
#pragma unroll
  for (int off = 32; off > 0; off >>= 1) x += __shfl_xor(x, off, 64);
  return x;
}

// ---------------------------------------------------------------- fp32 GEMM
// C[M,N] = A[M,K] @ B[K,N].  BM=BN=128, BK=16, 256 threads, 8x8 per thread.
// GATHER: A row r is embed_table[rowidx[r]].
template<bool GATHER>
__global__ __launch_bounds__(256) void gemm128(
    const float* __restrict__ A, const float* __restrict__ Bm,
    float* __restrict__ C, int M, int N, int K, const int* __restrict__ rowidx) {
  constexpr int BK = 16;
  __shared__ __align__(16) float As[BK][128];   // transposed: [k][m]
  __shared__ __align__(16) float Bs[BK][128];
  const int tid = threadIdx.x;
  const int bn = blockIdx.x * 128;
  const int bm = blockIdx.y * 128;
  const int tx = tid & 15, ty = tid >> 4;

  // A staging: thread -> (row = tid>>1, k-offset = (tid&1)*8), loads 8 floats
  const int arow = tid >> 1;
  const int akq  = (tid & 1) * 8;
  const float* Ap;
  if constexpr (GATHER) Ap = A + (size_t)rowidx[bm + arow] * K;
  else                  Ap = A + (size_t)(bm + arow) * K;
  // B staging: thread -> (k-row = tid>>4, col = (tid&15)*8), loads 8 floats
  const int bkr = tid >> 4;
  const int bnq = (tid & 15) * 8;
  const float* Bp = Bm + (size_t)bkr * N + bn + bnq;

  float acc[8][8];
#pragma unroll
  for (int i = 0; i < 8; i++)
#pragma unroll
    for (int j = 0; j < 8; j++) acc[i][j] = 0.f;

  for (int k0 = 0; k0 < K; k0 += BK) {
    float4 a0 = *(const float4*)(Ap + k0 + akq);
    float4 a1 = *(const float4*)(Ap + k0 + akq + 4);
    float4 b0 = *(const float4*)(Bp + (size_t)k0 * N);
    float4 b1 = *(const float4*)(Bp + (size_t)k0 * N + 4);
    __syncthreads();
    As[akq + 0][arow] = a0.x; As[akq + 1][arow] = a0.y;
    As[akq + 2][arow] = a0.z; As[akq + 3][arow] = a0.w;
    As[akq + 4][arow] = a1.x; As[akq + 5][arow] = a1.y;
    As[akq + 6][arow] = a1.z; As[akq + 7][arow] = a1.w;
    *(float4*)&Bs[bkr][bnq]     = b0;
    *(float4*)&Bs[bkr][bnq + 4] = b1;
    __syncthreads();
#pragma unroll
    for (int kk = 0; kk < BK; kk++) {
      float4 av0 = *(const float4*)&As[kk][ty * 8];
      float4 av1 = *(const float4*)&As[kk][ty * 8 + 4];
      float4 bv0 = *(const float4*)&Bs[kk][tx * 8];
      float4 bv1 = *(const float4*)&Bs[kk][tx * 8 + 4];
      float a[8] = {av0.x, av0.y, av0.z, av0.w, av1.x, av1.y, av1.z, av1.w};
      float b[8] = {bv0.x, bv0.y, bv0.z, bv0.w, bv1.x, bv1.y, bv1.z, bv1.w};
#pragma unroll
      for (int i = 0; i < 8; i++)
#pragma unroll
        for (int j = 0; j < 8; j++) acc[i][j] = fmaf(a[i], b[j], acc[i][j]);
    }
  }
#pragma unroll
  for (int i = 0; i < 8; i++) {
    float4 c0 = {acc[i][0], acc[i][1], acc[i][2], acc[i][3]};
    float4 c1 = {acc[i][4], acc[i][5], acc[i][6], acc[i][7]};
    float* Cp = C + (size_t)(bm + ty * 8 + i) * N + bn + tx * 8;
    *(float4*)Cp       = c0;
    *(float4*)(Cp + 4) = c1;
  }
}

// ---------------------------------------------------------------- ba = x @ W_ba  (N=64)
__global__ __launch_bounds__(64) void ba_gemm(
    const int* __restrict__ ids, const float* __restrict__ emb,
    const float* __restrict__ Wba, float* __restrict__ ba) {
  __shared__ __align__(16) float xs[HH];
  const int r = blockIdx.x, tid = threadIdx.x;
  const float* xr = emb + (size_t)ids[r] * HH;
  for (int i = tid * 4; i < HH; i += 64 * 4)
    *(float4*)&xs[i] = *(const float4*)(xr + i);
  __syncthreads();
  float acc = 0.f;
  for (int k = 0; k < HH; k++) acc = fmaf(xs[k], Wba[k * 64 + tid], acc);
  ba[r * 64 + tid] = acc;
}

// ---------------------------------------------------------------- causal depthwise conv(K=4)+SiLU
// reads qkvz[:, :8192]; scatters to q[B,HK,T,DK], k[B,HK,T,DK], v[B,HV,T,DV]
__global__ __launch_bounds__(256) void conv_kernel(
    const float* __restrict__ qkvz, const float* __restrict__ convw,
    const float* __restrict__ convb, float* __restrict__ qh,
    float* __restrict__ kh, float* __restrict__ vh) {
  const int r = blockIdx.x;               // b*T + t
  const int b = r >> 10, t = r & 1023;
  const int c = blockIdx.y * 256 + threadIdx.x;
  float4 w = *(const float4*)(convw + c * 4);
  const float* col = qkvz + (size_t)r * QKVZ + c;
  float acc = convb[c];
  if (t >= 3) {
    acc = fmaf(col[-3 * QKVZ], w.x, acc);
    acc = fmaf(col[-2 * QKVZ], w.y, acc);
    acc = fmaf(col[-1 * QKVZ], w.z, acc);
    acc = fmaf(col[0],         w.w, acc);
  } else {
    const float wj[4] = {w.x, w.y, w.z, w.w};
#pragma unroll
    for (int j = 0; j < 4; j++) {
      int tt = t - 3 + j;
      if (tt >= 0) acc = fmaf(col[(j - 3) * (int)QKVZ], wj[j], acc);
    }
  }
  float s = acc / (1.f + expf(-acc));     // SiLU
  const int hi = (c >> 7) & 15, d = c & 127;
  if (c < QKD)            qh[((size_t)(b * HK + hi) * TT + t) * DK + d] = s;
  else if (c < 2 * QKD)   kh[((size_t)(b * HK + hi) * TT + t) * DK + d] = s;
  else {
    const int hv = (c - 2 * QKD) >> 7;
    vh[((size_t)(b * HV + hv) * TT + t) * DV + d] = s;
  }
}

// ---------------------------------------------------------------- per-head l2norm of q,k (in place)
__global__ __launch_bounds__(64) void l2norm_qk(float* __restrict__ qh, float* __restrict__ kh) {
  const int NQK = BB * HK * TT;           // 32768
  const int id = blockIdx.x;
  const bool isq = id < NQK;
  float* p = (isq ? qh : kh) + (size_t)(isq ? id : id - NQK) * DK;
  const int tid = threadIdx.x;
  float x0 = p[tid], x1 = p[tid + 64];
  float ss = wave64_sum(x0 * x0 + x1 * x1);
  float r = rsqrtf(ss + FEPS);
  if (isq) r *= 0.08838834764831845f;     // DK^-0.5
  p[tid] = x0 * r;
  p[tid + 64] = x1 * r;
}

// ---------------------------------------------------------------- beta, g from ba
__global__ __launch_bounds__(256) void bg_kernel(
    const float* __restrict__ ba, const float* __restrict__ A_log,
    const float* __restrict__ dt_bias, float* __restrict__ g,
    float* __restrict__ beta) {
  const int idx = blockIdx.x * 256 + threadIdx.x;  // (b*HV + h)*T + t
  const int t = idx & (TT - 1);
  const int h = (idx >> 10) & (HV - 1);
  const int b = idx >> 15;
  const float* bar = ba + (size_t)(b * TT + t) * 64;
  beta[idx] = 1.f / (1.f + expf(-bar[h]));
  float x = bar[32 + h] + dt_bias[h];
  float sp = (x > 20.f) ? x : log1pf(expf(x));
  g[idx] = -expf(A_log[h]) * sp;
}

// ---------------------------------------------------------------- gated delta-rule scan
// one block per (b,h); 256 threads; column v = tid>>1, half = tid&1 owns S[half*64:+64][v]
// Reference step: S = S*exp(g); kv = k . S(decayed); delta = (v-kv)*beta;
//                 S += k (x) delta; o = q . S
// Since decay is a per-head scalar, k.(S*d) == d*(k.S) -> compute kv from old S
// and scale by d (the round-1 bug was omitting this scale).
__global__ __launch_bounds__(256) void scan_kernel(
    const float* __restrict__ qh, const float* __restrict__ kh,
    const float* __restrict__ vh, const float* __restrict__ g,
    const float* __restrict__ beta, float* __restrict__ o) {
  const int bh = blockIdx.x;
  const int b = bh >> 5, h = bh & 31, hkid = h >> 1;
  const float* qp = qh + (size_t)(b * HK + hkid) * TT * DK;
  const float* kp = kh + (size_t)(b * HK + hkid) * TT * DK;
  const float* vp = vh + (size_t)bh * TT * DV;
  const float* gp = g + (size_t)bh * TT;
  const float* bp = beta + (size_t)bh * TT;
  const int tid = threadIdx.x;
  const int v = tid >> 1, half = tid & 1;
  __shared__ __align__(16) float qs[CH * 128], ks[CH * 128], vs[CH * 128], os[CH * 128];
  __shared__ float dsc[CH], bsc[CH];
  float S[64];
#pragma unroll
  for (int i = 0; i < 64; i++) S[i] = 0.f;

  for (int t0 = 0; t0 < TT; t0 += CH) {
    { // stage chunk
      const int base = tid * 8;
      *(float4*)&qs[base]     = *(const float4*)(qp + t0 * 128 + base);
      *(float4*)&qs[base + 4] = *(const float4*)(qp + t0 * 128 + base + 4);
      *(float4*)&ks[base]     = *(const float4*)(kp + t0 * 128 + base);
      *(float4*)&ks[base + 4] = *(const float4*)(kp + t0 * 128 + base + 4);
      *(float4*)&vs[base]     = *(const float4*)(vp + t0 * 128 + base);
      *(float4*)&vs[base + 4] = *(const float4*)(vp + t0 * 128 + base + 4);
      if (tid < CH) { dsc[tid] = expf(gp[t0 + tid]); bsc[tid] = bp[t0 + tid]; }
    }
    __syncthreads();
    for (int i = 0; i < CH; i++) {
      const float d = dsc[i], bt = bsc[i];
      const float* kk = &ks[i * 128 + half * 64];
      const float* qq = &qs[i * 128 + half * 64];
      // kv = d * (k . S_old)  == k . (S_old * d)   [decayed-state prediction]
      float kp0 = 0.f, kp1 = 0.f, kp2 = 0.f, kp3 = 0.f;
#pragma unroll
      for (int j = 0; j < 64; j += 4) {
        float4 k4 = *(const float4*)&kk[j];
        kp0 = fmaf(k4.x, S[j],     kp0);
        kp1 = fmaf(k4.y, S[j + 1], kp1);
        kp2 = fmaf(k4.z, S[j + 2], kp2);
        kp3 = fmaf(k4.w, S[j + 3], kp3);
      }
      float kvp = (kp0 + kp1) + (kp2 + kp3);
      float kv = d * (kvp + __shfl_xor(kvp, 1, 64));
      float delta = (vs[i * 128 + v] - kv) * bt;
      // S = S*exp(g) + k*delta; o = q . S
      float o0 = 0.f, o1 = 0.f, o2 = 0.f, o3 = 0.f;
#pragma unroll
      for (int j = 0; j < 64; j += 4) {
        float4 k4 = *(const float4*)&kk[j];
        float4 q4 = *(const float4*)&qq[j];
        S[j]     = fmaf(k4.x, delta, S[j]     * d);
        S[j + 1] = fmaf(k4.y, delta, S[j + 1] * d);
        S[j + 2] = fmaf(k4.z, delta, S[j + 2] * d);
        S[j + 3] = fmaf(k4.w, delta, S[j + 3] * d);
        o0 = fmaf(q4.x, S[j],     o0);
        o1 = fmaf(q4.y, S[j + 1], o1);
        o2 = fmaf(q4.z, S[j + 2], o2);
        o3 = fmaf(q4.w, S[j + 3], o3);
      }
      float op_ = (o0 + o1) + (o2 + o3);
      float oo = op_ + __shfl_xor(op_, 1, 64);
      if (!half) os[i * 128 + v] = oo;
    }
    __syncthreads();
    { // write chunk: o[b, t, h, :]  (row-major [B*T, HV*DV])
      const int base = tid * 8;
      const int i = base >> 7, dd = base & 127;
      float4 o0 = *(float4*)&os[base];
      float4 o1 = *(float4*)&os[base + 4];
      float* outp = o + ((size_t)(b * TT + t0 + i) * HV + h) * DV + dd;
      *(float4*)outp       = o0;
      *(float4*)(outp + 4) = o1;
    }
    __syncthreads();
  }
}

// ---------------------------------------------------------------- gate with silu(z) + per-head RMSNorm
__global__ __launch_bounds__(64) void gate_norm(
    float* __restrict__ o, const float* __restrict__ qkvz,
    const float* __restrict__ norm_w) {
  const int id = blockIdx.x;              // (b*T+t)*HV + h
  const int row = id >> 5, h = id & 31;
  float* op = o + (size_t)id * DV;
  const float* zp = qkvz + (size_t)row * QKVZ + 2 * QKD + VD + h * DV;
  const int tid = threadIdx.x;
  float x0 = op[tid], x1 = op[tid + 64];
  float z0 = zp[tid], z1 = zp[tid + 64];
  x0 *= z0 / (1.f + expf(-z0));
  x1 *= z1 / (1.f + expf(-z1));
  float ss = wave64_sum(x0 * x0 + x1 * x1);
  float r = rsqrtf(ss * (1.f / 128.f) + FEPS);
  op[tid]      = x0 * r * norm_w[tid];
  op[tid + 64] = x1 * r * norm_w[tid + 64];
}

// ---------------------------------------------------------------- launch
extern "C" void kernel_launch(void* const* d_in, const int* in_sizes, int n_in,
                              void* d_out, int out_size, void* d_ws, size_t ws_size,
                              hipStream_t stream) {
  const int*   ids     = (const int*)d_in[0];
  const float* emb     = (const float*)d_in[1];
  const float* Wqkvz   = (const float*)d_in[2];
  const float* Wba     = (const float*)d_in[3];
  const float* convw   = (const float*)d_in[4];
  const float* convb   = (const float*)d_in[5];
  const float* A_log   = (const float*)d_in[6];
  const float* dt_bias = (const float*)d_in[7];
  const float* norm_w  = (const float*)d_in[8];
  const float* Wout    = (const float*)d_in[9];
  const float* Wlm     = (const float*)d_in[10];
  float* out = (float*)d_out;

  float* p = (float*)d_ws;
  float* qkvz  = p; p += (size_t)MM * QKVZ;        // 25.2M  (96 MB)
  float* ba    = p; p += (size_t)MM * 64;
  float* qh    = p; p += (size_t)BB * HK * TT * DK;
  float* kh    = p; p += (size_t)BB * HK * TT * DK;
  float* vh    = p; p += (size_t)BB * HV * TT * DV;
  float* gbuf  = p; p += (size_t)BB * HV * TT;
  float* betab = p; p += (size_t)BB * HV * TT;
  float* obuf  = p; p += (size_t)MM * VD;
  float* h2    = p; p += (size_t)MM * HH;

  gemm128<true><<<dim3(QKVZ / 128, MM / 128), 256, 0, stream>>>(
      emb, Wqkvz, qkvz, MM, QKVZ, HH, ids);
  ba_gemm<<<MM, 64, 0, stream>>>(ids, emb, Wba, ba);
  conv_kernel<<<dim3(MM, CONVD / 256), 256, 0, stream>>>(
      qkvz, convw, convb, qh, kh, vh);
  l2norm_qk<<<2 * BB * HK * TT, 64, 0, stream>>>(qh, kh);
  bg_kernel<<<(BB * HV * TT) / 256, 256, 0, stream>>>(ba, A_log, dt_bias, gbuf, betab);
  scan_kernel<<<BB * HV, 256, 0, stream>>>(qh, kh, vh, gbuf, betab, obuf);
  gate_norm<<<MM * HV, 64, 0, stream>>>(obuf, qkvz, norm_w);
  gemm128<false><<<dim3(HH / 128, MM / 128), 256, 0, stream>>>(
      obuf, Wout, h2, MM, HH, VD, nullptr);
  gemm128<false><<<dim3(VV / 128, MM / 128), 256, 0, stream>>>(
      h2, Wlm, out, MM, VV, HH, nullptr);
}